// Round 1
// baseline (270.338 us; speedup 1.0000x reference)
//
#include <hip/hip_runtime.h>
#include <math.h>

// Volume dims (fixed by the problem: IMG_SHAPE = (256,256,256))
#define DD 256
#define HH 256
#define WW 256

// ---------------------------------------------------------------------------
// Kernel 1: single thread computes the 3x4 resampling transform T (rows 0..2
// of inv(flo_v2r) @ T_rig @ ref_v2r) and writes 12 floats into workspace.
// ---------------------------------------------------------------------------
__global__ void compute_T_kernel(const float* __restrict__ angle,
                                 const float* __restrict__ trans,
                                 const float* __restrict__ ref_v2r,
                                 const float* __restrict__ flo_v2r,
                                 const float* __restrict__ cog,
                                 float* __restrict__ Tout /* 12 floats */) {
    if (blockIdx.x != 0 || threadIdx.x != 0) return;

    const float ax = angle[0], ay = angle[1], az = angle[2];
    const float cx = cosf(ax), sx = sinf(ax);
    const float cy = cosf(ay), sy = sinf(ay);
    const float cz = cosf(az), sz = sinf(az);

    // R = Rx @ Ry @ Rz
    // Rx@Ry = [[cy,0,sy],[sx*sy,cx,-sx*cy],[-cx*sy,sx,cx*cy]]
    float R[3][3];
    const float a00 = cy,      a01 = 0.0f, a02 = sy;
    const float a10 = sx * sy, a11 = cx,   a12 = -sx * cy;
    const float a20 = -cx * sy, a21 = sx,  a22 = cx * cy;
    R[0][0] = a00 * cz + a01 * sz; R[0][1] = -a00 * sz + a01 * cz; R[0][2] = a02;
    R[1][0] = a10 * cz + a11 * sz; R[1][1] = -a10 * sz + a11 * cz; R[1][2] = a12;
    R[2][0] = a20 * cz + a21 * sz; R[2][1] = -a20 * sz + a21 * cz; R[2][2] = a22;

    // T_rig = Tci @ Tt @ Tr @ Tc : linear part R, translation cog + t - R@cog
    float Trig[4][4];
    for (int r = 0; r < 4; ++r)
        for (int c = 0; c < 4; ++c)
            Trig[r][c] = (r == c) ? 1.0f : 0.0f;
    for (int r = 0; r < 3; ++r) {
        for (int c = 0; c < 3; ++c) Trig[r][c] = R[r][c];
        Trig[r][3] = cog[r] + trans[r]
                   - (R[r][0] * cog[0] + R[r][1] * cog[1] + R[r][2] * cog[2]);
    }

    // invF = inv(flo_v2r) via Gauss-Jordan with partial pivoting
    float A[4][8];
    for (int r = 0; r < 4; ++r) {
        for (int c = 0; c < 4; ++c) {
            A[r][c] = flo_v2r[r * 4 + c];
            A[r][c + 4] = (r == c) ? 1.0f : 0.0f;
        }
    }
    for (int col = 0; col < 4; ++col) {
        int piv = col;
        float best = fabsf(A[col][col]);
        for (int r = col + 1; r < 4; ++r) {
            float v = fabsf(A[r][col]);
            if (v > best) { best = v; piv = r; }
        }
        if (piv != col) {
            for (int c = 0; c < 8; ++c) {
                float t = A[col][c]; A[col][c] = A[piv][c]; A[piv][c] = t;
            }
        }
        const float inv = 1.0f / A[col][col];
        for (int c = 0; c < 8; ++c) A[col][c] *= inv;
        for (int r = 0; r < 4; ++r) {
            if (r == col) continue;
            const float f = A[r][col];
            for (int c = 0; c < 8; ++c) A[r][c] -= f * A[col][c];
        }
    }

    // M1 = Trig @ ref_v2r ; M = invF @ M1 ; store rows 0..2 of M
    float M1[4][4];
    for (int r = 0; r < 4; ++r)
        for (int c = 0; c < 4; ++c) {
            float s = 0.0f;
            for (int k = 0; k < 4; ++k) s += Trig[r][k] * ref_v2r[k * 4 + c];
            M1[r][c] = s;
        }
    for (int r = 0; r < 3; ++r)
        for (int c = 0; c < 4; ++c) {
            float s = 0.0f;
            for (int k = 0; k < 4; ++k) s += A[r][k + 4] * M1[k][c];
            Tout[r * 4 + c] = s;
        }
}

// ---------------------------------------------------------------------------
// Kernel 2: trilinear warp. One block per (i,j) row, 256 threads over k.
// ---------------------------------------------------------------------------
__global__ __launch_bounds__(256) void warp_kernel(
        const float* __restrict__ vol,
        const float* __restrict__ T,
        float* __restrict__ out) {
    __shared__ float Ts[12];
    if (threadIdx.x < 12) Ts[threadIdx.x] = T[threadIdx.x];
    __syncthreads();

    const int bid = blockIdx.x;          // = i * HH + j
    const int i = bid >> 8;
    const int j = bid & 255;
    const int k = threadIdx.x;

    const float gi = (float)i, gj = (float)j, gk = (float)k;
    float di = Ts[0] * gi + Ts[1] * gj + Ts[2]  * gk + Ts[3];
    float dj = Ts[4] * gi + Ts[5] * gj + Ts[6]  * gk + Ts[7];
    float dk = Ts[8] * gi + Ts[9] * gj + Ts[10] * gk + Ts[11];

    const bool ok = (di >= 0.0f) & (di <= (float)(DD - 1)) &
                    (dj >= 0.0f) & (dj <= (float)(HH - 1)) &
                    (dk >= 0.0f) & (dk <= (float)(WW - 1));

    di = fminf(fmaxf(di, 0.0f), (float)(DD - 1));
    dj = fminf(fmaxf(dj, 0.0f), (float)(HH - 1));
    dk = fminf(fmaxf(dk, 0.0f), (float)(WW - 1));

    const int fi = (int)floorf(di);
    const int fj = (int)floorf(dj);
    const int fk = (int)floorf(dk);
    const int ci = min(fi + 1, DD - 1);
    const int cj = min(fj + 1, HH - 1);
    const int ck = min(fk + 1, WW - 1);

    const float wi = di - (float)fi;
    const float wj = dj - (float)fj;
    const float wk = dk - (float)fk;

    const int fi_o = fi << 16, ci_o = ci << 16;
    const int fj_o = fj << 8,  cj_o = cj << 8;

    const float v000 = vol[fi_o + fj_o + fk];
    const float v001 = vol[fi_o + fj_o + ck];
    const float v010 = vol[fi_o + cj_o + fk];
    const float v011 = vol[fi_o + cj_o + ck];
    const float v100 = vol[ci_o + fj_o + fk];
    const float v101 = vol[ci_o + fj_o + ck];
    const float v110 = vol[ci_o + cj_o + fk];
    const float v111 = vol[ci_o + cj_o + ck];

    // nested lerp: along k, then j, then i
    const float c00 = v000 + (v001 - v000) * wk;
    const float c01 = v010 + (v011 - v010) * wk;
    const float c10 = v100 + (v101 - v100) * wk;
    const float c11 = v110 + (v111 - v110) * wk;
    const float c0  = c00 + (c01 - c00) * wj;
    const float c1  = c10 + (c11 - c10) * wj;
    const float val = c0 + (c1 - c0) * wi;

    out[(i << 16) + (j << 8) + k] = ok ? val : 0.0f;
}

extern "C" void kernel_launch(void* const* d_in, const int* in_sizes, int n_in,
                              void* d_out, int out_size, void* d_ws, size_t ws_size,
                              hipStream_t stream) {
    const float* image_targ  = (const float*)d_in[0];
    const float* angle       = (const float*)d_in[1];
    const float* translation = (const float*)d_in[2];
    const float* ref_v2r     = (const float*)d_in[3];
    const float* flo_v2r     = (const float*)d_in[4];
    const float* cog         = (const float*)d_in[5];
    float* out = (float*)d_out;
    float* Tws = (float*)d_ws;   // 12 floats

    compute_T_kernel<<<1, 64, 0, stream>>>(angle, translation, ref_v2r,
                                           flo_v2r, cog, Tws);
    warp_kernel<<<DD * HH, WW, 0, stream>>>(image_targ, Tws, out);
}

// Round 3
// 247.989 us; speedup vs baseline: 1.0901x; 1.0901x over previous
//
#include <hip/hip_runtime.h>
#include <math.h>

// Volume dims (fixed by the problem: IMG_SHAPE = (256,256,256))
#define DD 256
#define HH 256
#define WW 256

// ---------------------------------------------------------------------------
// Fused kernel: thread 0 of each block computes the 3x4 resampling transform
// T = rows 0..2 of inv(flo_v2r) @ T_rig @ ref_v2r into LDS (cheap closed-form
// adjugate inverse, ~300 VALU ops, hidden under other waves' memory latency),
// then all 256 threads do one trilinear-warp voxel each.
//
// Block->voxel mapping is XCD-aware: bid&7 selects one of 8 128^3 bricks
// (2x2x2 decomposition), so each XCD's private 4MiB L2 only ever sees its
// own brick + rotation halo (~15 MB bbox) instead of the whole 64 MB volume.
// Within a brick, tiles sweep k fastest, then j, then i, keeping the live
// input window (~200 KB) L2-resident. Output uses nontemporal stores so the
// 64 MB write stream does not evict the gather working set from L2.
// ---------------------------------------------------------------------------
__global__ __launch_bounds__(256) void warp_kernel(
        const float* __restrict__ vol,
        const float* __restrict__ angle,
        const float* __restrict__ trans,
        const float* __restrict__ ref_v2r,
        const float* __restrict__ flo_v2r,
        const float* __restrict__ cog,
        float* __restrict__ out) {
    __shared__ float Ts[12];

    if (threadIdx.x == 0) {
        const float ax = angle[0], ay = angle[1], az = angle[2];
        const float cx = cosf(ax), sx = sinf(ax);
        const float cy = cosf(ay), sy = sinf(ay);
        const float cz = cosf(az), sz = sinf(az);

        // R = Rx @ Ry @ Rz ;  Rx@Ry = [[cy,0,sy],[sx*sy,cx,-sx*cy],[-cx*sy,sx,cx*cy]]
        float R[3][3];
        const float a00 = cy,       a01 = 0.0f, a02 = sy;
        const float a10 = sx * sy,  a11 = cx,   a12 = -sx * cy;
        const float a20 = -cx * sy, a21 = sx,   a22 = cx * cy;
        R[0][0] = a00 * cz + a01 * sz; R[0][1] = -a00 * sz + a01 * cz; R[0][2] = a02;
        R[1][0] = a10 * cz + a11 * sz; R[1][1] = -a10 * sz + a11 * cz; R[1][2] = a12;
        R[2][0] = a20 * cz + a21 * sz; R[2][1] = -a20 * sz + a21 * cz; R[2][2] = a22;

        // T_rig: linear part R, translation cog + t - R@cog
        float Trig[4][4];
        for (int r = 0; r < 4; ++r)
            for (int c = 0; c < 4; ++c)
                Trig[r][c] = (r == c) ? 1.0f : 0.0f;
        for (int r = 0; r < 3; ++r) {
            for (int c = 0; c < 3; ++c) Trig[r][c] = R[r][c];
            Trig[r][3] = cog[r] + trans[r]
                       - (R[r][0] * cog[0] + R[r][1] * cog[1] + R[r][2] * cog[2]);
        }

        // Closed-form 4x4 inverse of flo_v2r (MESA adjugate; row-major in ->
        // row-major inverse out, since inv(A^T)^T = inv(A)).
        float m[16], inv[16];
        for (int q = 0; q < 16; ++q) m[q] = flo_v2r[q];
        inv[0]  =  m[5]*m[10]*m[15] - m[5]*m[11]*m[14] - m[9]*m[6]*m[15]
                 + m[9]*m[7]*m[14] + m[13]*m[6]*m[11] - m[13]*m[7]*m[10];
        inv[4]  = -m[4]*m[10]*m[15] + m[4]*m[11]*m[14] + m[8]*m[6]*m[15]
                 - m[8]*m[7]*m[14] - m[12]*m[6]*m[11] + m[12]*m[7]*m[10];
        inv[8]  =  m[4]*m[9]*m[15] - m[4]*m[11]*m[13] - m[8]*m[5]*m[15]
                 + m[8]*m[7]*m[13] + m[12]*m[5]*m[11] - m[12]*m[7]*m[9];
        inv[12] = -m[4]*m[9]*m[14] + m[4]*m[10]*m[13] + m[8]*m[5]*m[14]
                 - m[8]*m[6]*m[13] - m[12]*m[5]*m[10] + m[12]*m[6]*m[9];
        inv[1]  = -m[1]*m[10]*m[15] + m[1]*m[11]*m[14] + m[9]*m[2]*m[15]
                 - m[9]*m[3]*m[14] - m[13]*m[2]*m[11] + m[13]*m[3]*m[10];
        inv[5]  =  m[0]*m[10]*m[15] - m[0]*m[11]*m[14] - m[8]*m[2]*m[15]
                 + m[8]*m[3]*m[14] + m[12]*m[2]*m[11] - m[12]*m[3]*m[10];
        inv[9]  = -m[0]*m[9]*m[15] + m[0]*m[11]*m[13] + m[8]*m[1]*m[15]
                 - m[8]*m[3]*m[13] - m[12]*m[1]*m[11] + m[12]*m[3]*m[9];
        inv[13] =  m[0]*m[9]*m[14] - m[0]*m[10]*m[13] - m[8]*m[1]*m[14]
                 + m[8]*m[2]*m[13] + m[12]*m[1]*m[10] - m[12]*m[2]*m[9];
        inv[2]  =  m[1]*m[6]*m[15] - m[1]*m[7]*m[14] - m[5]*m[2]*m[15]
                 + m[5]*m[3]*m[14] + m[13]*m[2]*m[7] - m[13]*m[3]*m[6];
        inv[6]  = -m[0]*m[6]*m[15] + m[0]*m[7]*m[14] + m[4]*m[2]*m[15]
                 - m[4]*m[3]*m[14] - m[12]*m[2]*m[7] + m[12]*m[3]*m[6];
        inv[10] =  m[0]*m[5]*m[15] - m[0]*m[7]*m[13] - m[4]*m[1]*m[15]
                 + m[4]*m[3]*m[13] + m[12]*m[1]*m[7] - m[12]*m[3]*m[5];
        inv[14] = -m[0]*m[5]*m[14] + m[0]*m[6]*m[13] + m[4]*m[1]*m[14]
                 - m[4]*m[2]*m[13] - m[12]*m[1]*m[6] + m[12]*m[2]*m[5];
        inv[3]  = -m[1]*m[6]*m[11] + m[1]*m[7]*m[10] + m[5]*m[2]*m[11]
                 - m[5]*m[3]*m[10] - m[9]*m[2]*m[7] + m[9]*m[3]*m[6];
        inv[7]  =  m[0]*m[6]*m[11] - m[0]*m[7]*m[10] - m[4]*m[2]*m[11]
                 + m[4]*m[3]*m[10] + m[8]*m[2]*m[7] - m[8]*m[3]*m[6];
        inv[11] = -m[0]*m[5]*m[11] + m[0]*m[7]*m[9] + m[4]*m[1]*m[11]
                 - m[4]*m[3]*m[9] - m[8]*m[1]*m[7] + m[8]*m[3]*m[5];
        inv[15] =  m[0]*m[5]*m[10] - m[0]*m[6]*m[9] - m[4]*m[1]*m[10]
                 + m[4]*m[2]*m[9] + m[8]*m[1]*m[6] - m[8]*m[2]*m[5];
        const float det = m[0]*inv[0] + m[1]*inv[4] + m[2]*inv[8] + m[3]*inv[12];
        const float rdet = 1.0f / det;

        // M1 = Trig @ ref_v2r ; T = invF @ M1 ; rows 0..2 -> LDS
        float M1[4][4];
        for (int r = 0; r < 4; ++r)
            for (int c = 0; c < 4; ++c) {
                float s = 0.0f;
                for (int q = 0; q < 4; ++q) s += Trig[r][q] * ref_v2r[q * 4 + c];
                M1[r][c] = s;
            }
        for (int r = 0; r < 3; ++r)
            for (int c = 0; c < 4; ++c) {
                float s = 0.0f;
                for (int q = 0; q < 4; ++q) s += (inv[r * 4 + q] * rdet) * M1[q][c];
                Ts[r * 4 + c] = s;
            }
    }
    __syncthreads();

    // XCD-aware brick mapping: bid&7 -> 2x2x2 brick of 128^3; within an XCD,
    // tiles sweep k fastest, then j, then i.
    const int bid = blockIdx.x;
    const int xcd = bid & 7;
    const int n = bid >> 3;          // 0..8191 per brick
    const int bi = (xcd >> 2) & 1;
    const int bj = (xcd >> 1) & 1;
    const int bk = xcd & 1;
    const int kt = n & 1;            // 2 k-tiles of 64
    const int jt = (n >> 1) & 31;    // 32 j-tiles of 4
    const int it = n >> 6;           // 128 i-planes

    const int tx = threadIdx.x & 63; // k within tile (wave = contiguous k)
    const int ty = threadIdx.x >> 6; // j within tile

    const int i = (bi << 7) + it;
    const int j = (bj << 7) + (jt << 2) + ty;
    const int k = (bk << 7) + (kt << 6) + tx;

    const float gi = (float)i, gj = (float)j, gk = (float)k;
    float di = Ts[0] * gi + Ts[1] * gj + Ts[2]  * gk + Ts[3];
    float dj = Ts[4] * gi + Ts[5] * gj + Ts[6]  * gk + Ts[7];
    float dk = Ts[8] * gi + Ts[9] * gj + Ts[10] * gk + Ts[11];

    const bool ok = (di >= 0.0f) & (di <= (float)(DD - 1)) &
                    (dj >= 0.0f) & (dj <= (float)(HH - 1)) &
                    (dk >= 0.0f) & (dk <= (float)(WW - 1));

    di = fminf(fmaxf(di, 0.0f), (float)(DD - 1));
    dj = fminf(fmaxf(dj, 0.0f), (float)(HH - 1));
    dk = fminf(fmaxf(dk, 0.0f), (float)(WW - 1));

    const int fi = (int)di;
    const int fj = (int)dj;
    const int fk = (int)dk;
    const int ci = min(fi + 1, DD - 1);
    const int cj = min(fj + 1, HH - 1);
    const int ck = min(fk + 1, WW - 1);

    const float wi = di - (float)fi;
    const float wj = dj - (float)fj;
    const float wk = dk - (float)fk;

    const int fi_o = fi << 16, ci_o = ci << 16;
    const int fj_o = fj << 8,  cj_o = cj << 8;

    const float v000 = vol[fi_o + fj_o + fk];
    const float v001 = vol[fi_o + fj_o + ck];
    const float v010 = vol[fi_o + cj_o + fk];
    const float v011 = vol[fi_o + cj_o + ck];
    const float v100 = vol[ci_o + fj_o + fk];
    const float v101 = vol[ci_o + fj_o + ck];
    const float v110 = vol[ci_o + cj_o + fk];
    const float v111 = vol[ci_o + cj_o + ck];

    // nested lerp: along k, then j, then i
    const float c00 = v000 + (v001 - v000) * wk;
    const float c01 = v010 + (v011 - v010) * wk;
    const float c10 = v100 + (v101 - v100) * wk;
    const float c11 = v110 + (v111 - v110) * wk;
    const float c0  = c00 + (c01 - c00) * wj;
    const float c1  = c10 + (c11 - c10) * wj;
    const float val = c0 + (c1 - c0) * wi;

    __builtin_nontemporal_store(ok ? val : 0.0f, &out[(i << 16) + (j << 8) + k]);
}

extern "C" void kernel_launch(void* const* d_in, const int* in_sizes, int n_in,
                              void* d_out, int out_size, void* d_ws, size_t ws_size,
                              hipStream_t stream) {
    const float* image_targ  = (const float*)d_in[0];
    const float* angle       = (const float*)d_in[1];
    const float* translation = (const float*)d_in[2];
    const float* ref_v2r     = (const float*)d_in[3];
    const float* flo_v2r     = (const float*)d_in[4];
    const float* cog         = (const float*)d_in[5];
    float* out = (float*)d_out;

    warp_kernel<<<DD * HH, 256, 0, stream>>>(image_targ, angle, translation,
                                             ref_v2r, flo_v2r, cog, out);
}